// Round 2
// baseline (985.980 us; speedup 1.0000x reference)
//
#include <hip/hip_runtime.h>

typedef unsigned short ushort_t;

#define PI2 6.283185307179586f

__device__ inline float bf2f(ushort_t u){
  union { unsigned int i; float f; } x; x.i = ((unsigned int)u) << 16; return x.f;
}
__device__ inline ushort_t f2bf(float f){
  union { float f; unsigned int i; } x; x.f = f;
  unsigned int r = x.i + 0x7fffu + ((x.i >> 16) & 1u);  // RNE
  return (ushort_t)(r >> 16);
}
__device__ inline float fast_tanh(float x){
  float e = __expf(2.0f*x);
  return 1.0f - 2.0f/(e + 1.0f);
}

// ---------------- inner net: block = (i, g-quad), thread = j ----------------
__global__ __launch_bounds__(256) void inner_kernel(
    const float* __restrict__ z,       // [256]
    const float* __restrict__ log_w,   // [256]
    const float* __restrict__ icoef,   // [2][32]
    const float* __restrict__ w1,      // [1024][64]
    const float* __restrict__ w2,      // [16][64]
    float* __restrict__ out0)          // [16][256 j][256 i]
{
  const int tx = threadIdx.x;
  const int j = tx;
  const int i = blockIdx.x >> 2;
  const int q = blockIdx.x & 3;
  const int lane = tx & 63, wid = tx >> 6;
  __shared__ float sred[4];

  float zi = z[i];
  float zj = z[j];
  float lw = log_w[j];

  // fourier features for pair (i,j): xp_k = 2pi*(zi*c0k + zj*c1k)
  float ff[64];
  #pragma unroll
  for (int k = 0; k < 32; k++){
    float xp = PI2 * (zi*icoef[k] + zj*icoef[32+k]);
    float sv, cv;
    __sincosf(xp, &sv, &cv);
    ff[k] = cv; ff[32+k] = sv;
  }

  #pragma unroll 1
  for (int gg = 0; gg < 4; gg++){
    int g = q*4 + gg;
    const float* W = w1 + g*4096;
    float lg = 0.f;
    #pragma unroll 1
    for (int d = 0; d < 64; d += 2){
      const float* r0 = W + d*64;       // wave-uniform rows -> scalar loads
      float a0 = 0.f, a1 = 0.f;
      #pragma unroll
      for (int k = 0; k < 64; k++){
        a0 = fmaf(r0[k],    ff[k], a0);
        a1 = fmaf(r0[64+k], ff[k], a1);
      }
      lg = fmaf(w2[g*64+d],   fast_tanh(a0), lg);
      lg = fmaf(w2[g*64+d+1], fast_tanh(a1), lg);
    }
    // logit = -softplus(lg), stable
    float sp = fmaxf(lg, 0.f) + __logf(1.f + __expf(-fabsf(lg)));
    float logit = -sp;

    // block-wide logsumexp over j of (logit + log_w[j])
    float t = logit + lw;
    float m = t;
    #pragma unroll
    for (int o = 32; o > 0; o >>= 1) m = fmaxf(m, __shfl_xor(m, o, 64));
    if (lane == 0) sred[wid] = m;
    __syncthreads();
    m = fmaxf(fmaxf(sred[0], sred[1]), fmaxf(sred[2], sred[3]));
    __syncthreads();
    float e = __expf(t - m);
    float s = e;
    #pragma unroll
    for (int o = 32; o > 0; o >>= 1) s += __shfl_xor(s, o, 64);
    if (lane == 0) sred[wid] = s;
    __syncthreads();
    s = sred[0] + sred[1] + sred[2] + sred[3];
    __syncthreads();
    float lse = m + __logf(s);
    // inner_param[g][j][i] = exp(logit - lse + log_w[j])
    out0[g*65536 + j*256 + i] = __expf(logit - lse + lw);
  }
}

// ---------------- input net: block = (g, n-tile of 64) ----------------
__global__ __launch_bounds__(256) void input_kernel(
    const float* __restrict__ z,        // [256]
    const float* __restrict__ ipcoef,   // [32]
    const float* __restrict__ w1,       // [784][64][64]
    const float* __restrict__ w2,       // [784][256][64]
    float* __restrict__ out1)           // [784][256 n][256 c]
{
  const int tx = threadIdx.x;
  const int g  = blockIdx.x >> 2;
  const int nt = blockIdx.x & 3;
  const int n  = tx & 63;
  const int cq = tx >> 6;

  __shared__ float    sh_hi[64*64];        // [d][n]
  __shared__ ushort_t sh_logit[256*64];    // [c][(n+c)&63] bf16, swizzled
  __shared__ float    sm[4][64], ssv[4][64], slse[64];

  // phase 0: fourier features for this thread's n
  float zn = z[nt*64 + n];
  float ff[64];
  #pragma unroll
  for (int k = 0; k < 32; k++){
    float xp = PI2 * zn * ipcoef[k];
    float sv, cv;
    __sincosf(xp, &sv, &cv);
    ff[k] = cv; ff[32+k] = sv;
  }

  // phase 1: hi[d][n] = tanh(W1g[d,:] . ff), d split over cq
  const float* Wg = w1 + g*4096;
  #pragma unroll 1
  for (int d = cq*16; d < cq*16 + 16; d++){
    const float* r = Wg + d*64;            // wave-uniform
    float a0 = 0.f, a1 = 0.f;
    #pragma unroll
    for (int k = 0; k < 32; k++){
      a0 = fmaf(r[k],    ff[k],    a0);
      a1 = fmaf(r[32+k], ff[32+k], a1);
    }
    sh_hi[d*64 + n] = fast_tanh(a0 + a1);
  }
  __syncthreads();

  // phase 2: this thread's hi column into regs
  float hig[64];
  #pragma unroll
  for (int d = 0; d < 64; d++) hig[d] = sh_hi[d*64 + n];

  // phase 3: logits for c in [cq*64, cq*64+64), online logsumexp per (n,cq)
  const float* w2g = w2 + (size_t)g*16384;
  float m = -3.0e38f, s = 0.f;
  #pragma unroll 1
  for (int ci = 0; ci < 64; ci++){
    int c = cq*64 + ci;
    const float* wr = w2g + c*64;          // wave-uniform row
    float a0 = 0.f, a1 = 0.f;
    #pragma unroll
    for (int d = 0; d < 32; d++){
      a0 = fmaf(wr[d],    hig[d],    a0);
      a1 = fmaf(wr[32+d], hig[32+d], a1);
    }
    float v = a0 + a1;
    if (v <= m) { s += __expf(v - m); }
    else        { s = fmaf(s, __expf(m - v), 1.f); m = v; }
    sh_logit[c*64 + ((n + c) & 63)] = f2bf(v);
  }
  sm[cq][n] = m; ssv[cq][n] = s;
  __syncthreads();

  // phase 4: combine the 4 partial (m,s) per n
  if (tx < 64){
    float M = fmaxf(fmaxf(sm[0][tx], sm[1][tx]), fmaxf(sm[2][tx], sm[3][tx]));
    float S = ssv[0][tx]*__expf(sm[0][tx]-M) + ssv[1][tx]*__expf(sm[1][tx]-M)
            + ssv[2][tx]*__expf(sm[2][tx]-M) + ssv[3][tx]*__expf(sm[3][tx]-M);
    slse[tx] = M + __logf(S);
  }
  __syncthreads();

  // phase 5: out[g][n][c] = logit - lse, coalesced rows (c = tx)
  size_t base = (size_t)g*65536 + (size_t)nt*64*256;
  #pragma unroll 1
  for (int rr = 0; rr < 64; rr++){
    float v = bf2f(sh_logit[tx*64 + ((rr + tx) & 63)]);
    out1[base + (size_t)rr*256 + tx] = v - slse[rr];
  }
}

extern "C" void kernel_launch(void* const* d_in, const int* in_sizes, int n_in,
                              void* d_out, int out_size, void* d_ws, size_t ws_size,
                              hipStream_t stream)
{
  const float* z     = (const float*)d_in[0];
  const float* lw    = (const float*)d_in[1];
  const float* icoef = (const float*)d_in[2];
  const float* iw1   = (const float*)d_in[3];
  const float* iw2   = (const float*)d_in[4];
  const float* ipc   = (const float*)d_in[5];
  const float* inw1  = (const float*)d_in[6];
  const float* inw2  = (const float*)d_in[7];

  float* out0 = (float*)d_out;
  float* out1 = out0 + 16*256*256;

  hipLaunchKernelGGL(inner_kernel, dim3(1024), dim3(256), 0, stream, z, lw, icoef, iw1, iw2, out0);
  hipLaunchKernelGGL(input_kernel, dim3(3136), dim3(256), 0, stream, z, ipc, inw1, inw2, out1);
}

// Round 3
// 357.854 us; speedup vs baseline: 2.7553x; 2.7553x over previous
//
#include <hip/hip_runtime.h>

typedef unsigned short ushort_t;
typedef float f32x4 __attribute__((ext_vector_type(4)));
typedef __bf16 bf16x8 __attribute__((ext_vector_type(8)));

#define PI2 6.283185307179586f

__device__ inline float bf2f(ushort_t u){
  union { unsigned int i; float f; } x; x.i = ((unsigned int)u) << 16; return x.f;
}
__device__ inline float fast_tanh(float x){
  float e = __expf(2.0f*x);
  return 1.0f - 2.0f/(e + 1.0f);
}

// ============================ inner net ============================
// block = (i, g-quad): blockIdx = i*4 + gq. 256 threads = 4 waves.
// Per g: S[64 d][256 j] = W1g @ ff  (MFMA), logit[j] = -softplus(sum_d w2[g,d] tanh(S)),
// block softmax over j, out0[g][j][i] = exp(logit - lse + log_w[j]).
__global__ __launch_bounds__(256, 4) void inner_kernel(
    const float* __restrict__ z,       // [256]
    const float* __restrict__ log_w,   // [256]
    const float* __restrict__ icoef,   // [2][32]
    const float* __restrict__ w1,      // [1024][64]
    const float* __restrict__ w2,      // [16][64]
    float* __restrict__ out0)          // [16][256 j][256 i]
{
  const int tx   = threadIdx.x;
  const int lane = tx & 63, wid = tx >> 6;
  const int i    = blockIdx.x >> 2;
  const int gq   = blockIdx.x & 3;

  // ff pre-packed in B-fragment order: frag idx = (t*2+delta)*64 + lane, 8 bf16 each.
  // element: ff[k = 32*delta + 8*(lane>>4) + ii][j = 16*t + (lane&15)]
  __shared__ __bf16 sh_ffB[16 * 2 * 64 * 8];   // 32 KB
  __shared__ float  sredw[4][256];             // per-wave partial d-sums
  __shared__ float  sred4[4];

  const float zi = z[i];
  const float zj = z[tx];          // thread tx owns pair-column j = tx
  const float lw = log_w[tx];

  // ---- phase 0: fourier features, packed straight into fragment layout ----
  {
    const int t = tx >> 4, n = tx & 15;
    #pragma unroll
    for (int q = 0; q < 4; q++){
      union { __bf16 h[8]; uint4 v; } pc, ps;
      #pragma unroll
      for (int ii = 0; ii < 8; ii++){
        int k = 8*q + ii;
        float xp = PI2 * (zi*icoef[k] + zj*icoef[32+k]);
        float sv, cv;
        __sincosf(xp, &sv, &cv);
        pc.h[ii] = (__bf16)cv;     // rows 0..31  = cos
        ps.h[ii] = (__bf16)sv;     // rows 32..63 = sin
      }
      ((uint4*)sh_ffB)[(t*2+0)*64 + 16*q + n] = pc.v;
      ((uint4*)sh_ffB)[(t*2+1)*64 + 16*q + n] = ps.v;
    }
  }
  __syncthreads();

  const int w = wid;               // wave w owns d-tile [16w, 16w+16)
  #pragma unroll 1
  for (int gg = 0; gg < 4; gg++){
    const int g = gq*4 + gg;

    // A fragments: W1g rows d = 16w + (lane&15), k = (lane>>4)*8 + ii (+32)
    const float* Ar = w1 + (size_t)(g*64 + 16*w + (lane&15))*64 + (lane>>4)*8;
    bf16x8 A0, A1;
    #pragma unroll
    for (int ii = 0; ii < 8; ii++){
      A0[ii] = (__bf16)Ar[ii];
      A1[ii] = (__bf16)Ar[32+ii];
    }
    // w2 weights for this lane's 4 d-rows: d = 16w + 4*(lane>>4) + r
    const float4 w2v = *(const float4*)(w2 + g*64 + 16*w + 4*(lane>>4));

    float part[16];
    #pragma unroll 4
    for (int t = 0; t < 16; t++){
      bf16x8 B0 = *(const bf16x8*)(sh_ffB + ((size_t)(t*2+0)*64 + lane)*8);
      bf16x8 B1 = *(const bf16x8*)(sh_ffB + ((size_t)(t*2+1)*64 + lane)*8);
      f32x4 acc = {0.f, 0.f, 0.f, 0.f};
      acc = __builtin_amdgcn_mfma_f32_16x16x32_bf16(A0, B0, acc, 0, 0, 0);
      acc = __builtin_amdgcn_mfma_f32_16x16x32_bf16(A1, B1, acc, 0, 0, 0);
      float p = 0.f;
      p = fmaf(w2v.x, fast_tanh(acc[0]), p);
      p = fmaf(w2v.y, fast_tanh(acc[1]), p);
      p = fmaf(w2v.z, fast_tanh(acc[2]), p);
      p = fmaf(w2v.w, fast_tanh(acc[3]), p);
      part[t] = p;
    }
    // reduce over the 4 k-groups (d quadrants) inside the wave
    #pragma unroll
    for (int t = 0; t < 16; t++){
      float p = part[t];
      p += __shfl_xor(p, 16, 64);
      p += __shfl_xor(p, 32, 64);
      if ((lane >> 4) == 0) sredw[w][t*16 + lane] = p;
    }
    __syncthreads();

    // ---- block softmax over j (thread tx = j) ----
    float y = sredw[0][tx] + sredw[1][tx] + sredw[2][tx] + sredw[3][tx];
    float sp = fmaxf(y, 0.f) + __logf(1.f + __expf(-fabsf(y)));
    float tval = -sp + lw;                       // logit + log_w[j]
    float m = tval;
    #pragma unroll
    for (int o = 32; o > 0; o >>= 1) m = fmaxf(m, __shfl_xor(m, o, 64));
    if (lane == 0) sred4[wid] = m;
    __syncthreads();
    m = fmaxf(fmaxf(sred4[0], sred4[1]), fmaxf(sred4[2], sred4[3]));
    __syncthreads();
    float e = __expf(tval - m);
    float s = e;
    #pragma unroll
    for (int o = 32; o > 0; o >>= 1) s += __shfl_xor(s, o, 64);
    if (lane == 0) sred4[wid] = s;
    __syncthreads();
    s = sred4[0] + sred4[1] + sred4[2] + sred4[3];
    float lse = m + __logf(s);
    out0[(size_t)g*65536 + (size_t)tx*256 + i] = __expf(tval - lse);
    __syncthreads();   // protect sredw/sred4 for next g
  }
}

// ============================ input net ============================
// block = (g, n-tile of 64), XCD-swizzled so the 4 n-tiles of one g share L2.
__global__ __launch_bounds__(256, 3) void input_kernel(
    const float* __restrict__ z,        // [256]
    const float* __restrict__ ipc,      // [32]
    const float* __restrict__ w1,       // [784][64][64]
    const float* __restrict__ w2,       // [784][256][64]
    float* __restrict__ out1)           // [784][256 n][256 c]
{
  const int tx   = threadIdx.x;
  const int lane = tx & 63, wid = tx >> 6;
  const int b    = blockIdx.x;
  const int xcd  = b & 7;
  const int s    = b >> 3;              // 0..391
  const int g    = xcd*98 + (s >> 2);   // 4 consecutive slots -> same g, same XCD
  const int nt   = s & 3;

  __shared__ __bf16 sh_fB[4 * 2 * 64 * 8];   // ffi, B-frag packed, 8 KB
  __shared__ __bf16 sh_hB[4 * 2 * 64 * 8];   // hi,  B-frag packed, 8 KB
  __shared__ ushort_t sh_lg[64 * 260];       // logits bf16, [n][c] stride 260, 33.3 KB
  __shared__ float sm[4][64], ssv[4][64], slse[64];

  // ---- phase 0: ffi for the 64 local n, packed into B-fragment layout ----
  {
    const int n = tx & 63, q = tx >> 6;      // thread covers k = 8q..8q+7 for its n
    const int t = n >> 4, nn = n & 15;
    const float zn = z[nt*64 + n];
    union { __bf16 h[8]; uint4 v; } pc, ps;
    #pragma unroll
    for (int ii = 0; ii < 8; ii++){
      float xp = PI2 * zn * ipc[8*q + ii];
      float sv, cv;
      __sincosf(xp, &sv, &cv);
      pc.h[ii] = (__bf16)cv;
      ps.h[ii] = (__bf16)sv;
    }
    ((uint4*)sh_fB)[(t*2+0)*64 + 16*q + nn] = pc.v;
    ((uint4*)sh_fB)[(t*2+1)*64 + 16*q + nn] = ps.v;
  }
  __syncthreads();

  // ---- phase 1: hi = tanh(W1g @ ffi), wave w -> d-tile [16w,16w+16) ----
  {
    const int w = wid;
    const float* Ar = w1 + (size_t)g*4096 + (size_t)(16*w + (lane&15))*64 + (lane>>4)*8;
    bf16x8 A0, A1;
    #pragma unroll
    for (int ii = 0; ii < 8; ii++){
      A0[ii] = (__bf16)Ar[ii];
      A1[ii] = (__bf16)Ar[32+ii];
    }
    const int q2 = lane >> 4, nn = lane & 15;
    const int dlt = w >> 1;
    #pragma unroll
    for (int t = 0; t < 4; t++){
      bf16x8 B0 = *(const bf16x8*)(sh_fB + ((size_t)(t*2+0)*64 + lane)*8);
      bf16x8 B1 = *(const bf16x8*)(sh_fB + ((size_t)(t*2+1)*64 + lane)*8);
      f32x4 acc = {0.f, 0.f, 0.f, 0.f};
      acc = __builtin_amdgcn_mfma_f32_16x16x32_bf16(A0, B0, acc, 0, 0, 0);
      acc = __builtin_amdgcn_mfma_f32_16x16x32_bf16(A1, B1, acc, 0, 0, 0);
      // scatter tanh(hi) into B-fragment layout of sh_hB
      #pragma unroll
      for (int r = 0; r < 4; r++){
        int d  = 16*w + 4*q2 + r;
        int qB = (d & 31) >> 3, iB = d & 7;
        sh_hB[((size_t)(t*2+dlt)*64 + qB*16 + nn)*8 + iB] = (__bf16)fast_tanh(acc[r]);
      }
    }
  }
  __syncthreads();

  // ---- phase 2: logits = w2g @ hi; wave w -> c-tiles 4w..4w+3 ----
  {
    const int w = wid;
    const float* w2g = w2 + (size_t)g*16384;
    #pragma unroll 1
    for (int cc = 0; cc < 4; cc++){
      const int ct = 4*w + cc;
      const float* Ar = w2g + (size_t)(16*ct + (lane&15))*64 + (lane>>4)*8;
      bf16x8 A0, A1;
      #pragma unroll
      for (int ii = 0; ii < 8; ii++){
        A0[ii] = (__bf16)Ar[ii];
        A1[ii] = (__bf16)Ar[32+ii];
      }
      #pragma unroll
      for (int t = 0; t < 4; t++){
        bf16x8 B0 = *(const bf16x8*)(sh_hB + ((size_t)(t*2+0)*64 + lane)*8);
        bf16x8 B1 = *(const bf16x8*)(sh_hB + ((size_t)(t*2+1)*64 + lane)*8);
        f32x4 acc = {0.f, 0.f, 0.f, 0.f};
        acc = __builtin_amdgcn_mfma_f32_16x16x32_bf16(A0, B0, acc, 0, 0, 0);
        acc = __builtin_amdgcn_mfma_f32_16x16x32_bf16(A1, B1, acc, 0, 0, 0);
        // logits: c = 16ct + 4*(lane>>4) + r, n = 16t + (lane&15); pack 4 -> one 8B store
        int c0 = 16*ct + 4*(lane>>4);
        int nn = 16*t + (lane&15);
        union { ushort_t u[4]; uint2 v; } pk;
        #pragma unroll
        for (int r = 0; r < 4; r++){
          union { float f; unsigned int i; } x; x.f = acc[r];
          unsigned int rr = x.i + 0x7fffu + ((x.i >> 16) & 1u);
          pk.u[r] = (ushort_t)(rr >> 16);
        }
        *(uint2*)(sh_lg + (size_t)nn*260 + c0) = pk.v;
      }
    }
  }
  __syncthreads();

  // ---- phase 3: log_softmax over c, coalesced output ----
  {
    const int n = tx & 63, cq = tx >> 6;
    const ushort_t* row = sh_lg + (size_t)n*260 + cq*64;
    float m = -3.0e38f;
    #pragma unroll 4
    for (int ci = 0; ci < 64; ci++) m = fmaxf(m, bf2f(row[ci]));
    float s = 0.f;
    #pragma unroll 4
    for (int ci = 0; ci < 64; ci++) s += __expf(bf2f(row[ci]) - m);
    sm[cq][n] = m; ssv[cq][n] = s;
  }
  __syncthreads();
  if (tx < 64){
    float M = fmaxf(fmaxf(sm[0][tx], sm[1][tx]), fmaxf(sm[2][tx], sm[3][tx]));
    float S = ssv[0][tx]*__expf(sm[0][tx]-M) + ssv[1][tx]*__expf(sm[1][tx]-M)
            + ssv[2][tx]*__expf(sm[2][tx]-M) + ssv[3][tx]*__expf(sm[3][tx]-M);
    slse[tx] = M + __logf(S);
  }
  __syncthreads();
  {
    size_t base = (size_t)g*65536 + (size_t)nt*64*256;
    #pragma unroll 1
    for (int rr = 0; rr < 64; rr++){
      out1[base + (size_t)rr*256 + tx] = bf2f(sh_lg[(size_t)rr*260 + tx]) - slse[rr];
    }
  }
}

extern "C" void kernel_launch(void* const* d_in, const int* in_sizes, int n_in,
                              void* d_out, int out_size, void* d_ws, size_t ws_size,
                              hipStream_t stream)
{
  const float* z     = (const float*)d_in[0];
  const float* lw    = (const float*)d_in[1];
  const float* icoef = (const float*)d_in[2];
  const float* iw1   = (const float*)d_in[3];
  const float* iw2   = (const float*)d_in[4];
  const float* ipc   = (const float*)d_in[5];
  const float* inw1  = (const float*)d_in[6];
  const float* inw2  = (const float*)d_in[7];

  float* out0 = (float*)d_out;
  float* out1 = out0 + (size_t)16*256*256;

  hipLaunchKernelGGL(inner_kernel, dim3(1024), dim3(256), 0, stream, z, lw, icoef, iw1, iw2, out0);
  hipLaunchKernelGGL(input_kernel, dim3(3136), dim3(256), 0, stream, z, ipc, inw1, inw2, out1);
}